// Round 5
// baseline (449.162 us; speedup 1.0000x reference)
//
#include <hip/hip_runtime.h>

// Problem constants (from reference)
constexpr int B    = 1024;
constexpr int L    = 50;
constexpr int S    = 256;
constexpr int H    = 4;
constexpr int E    = 64;
constexpr int HID  = 64;
constexpr int SUPP = 10000;
constexpr int RW   = 13;   // history rows per wave (4 waves * 13 = 52 >= L)
constexpr int LP   = 52;   // padded history rows

// Branch-free tanh via exp2-based __expf; clamp keeps e finite. Rel err ~1e-6.
__device__ __forceinline__ float tanh_fast(float x) {
    const float xc = fminf(fmaxf(x, -15.0f), 15.0f);
    const float e  = __expf(2.0f * xc);
    return (e - 1.0f) * __builtin_amdgcn_rcpf(e + 1.0f);
}

// Broadcast lane l's value (l wave-uniform) -> v_readlane -> SGPR.
__device__ __forceinline__ float lanebc(float v, int l) {
    return __int_as_float(__builtin_amdgcn_readlane(__float_as_int(v), l));
}

// ---------------------------------------------------------------------------
// Kernel 1: fused pre-work.  256 threads (4 waves), __launch_bounds__(256,4):
// VGPR cap 128 -- enough for the 64-float per-lane weight column to stay
// register-resident (round-0 evidence: wcol[64] fit at VGPR=72; round-1's
// VGPR=60 demoted it to ~830 in-loop global loads per wave = the bottleneck;
// rounds 2/4 showed bigger blockings spill to scratch).
//   blockIdx.y in {0,1}: user_fea_encode(call=y) + per-head q projection
//     (wave == head); fea never touches global memory.
//   blockIdx.y == 2:     K_supp[h][j][:] = tgt_user_emb[supp_users[j]] @ Wk[h]
// Hot dot products: weights in VGPRs (const-indexed, fully unrolled) x rows
// broadcast via uniform-address float4 LDS reads.  No global loads, no
// readlanes in the inner loops.
// Pad check: reference's hist.sum(-1)==0 is a.s. equivalent to l>=hlen
// (Gaussian embeddings never sum to exactly 0).
// Reference quirks preserved: src_item_emb for BOTH encode calls; encoder
// softmax has no max-subtract, padded rows contribute exp(0)=1; denom+1e-12.
// ---------------------------------------------------------------------------
__global__ __launch_bounds__(256, 4) void pre_kernel(
    const int* __restrict__ x,            // (B,2)  [:,0]=user_id
    const int* __restrict__ src_his,      // (B,L)
    const int* __restrict__ src_hl,       // (B,)
    const int* __restrict__ tgt_his,      // (B,L)
    const int* __restrict__ tgt_hl,       // (B,)
    const float* __restrict__ item_emb,   // src_item_emb -- always src!
    const float* __restrict__ src_user_emb,
    const float* __restrict__ tgt_user_emb,
    const int* __restrict__ supp_users,   // (SUPP,)
    const float* __restrict__ W_att_w,    // (E,E)
    const float* __restrict__ W_att_b,    // (E,)
    const float* __restrict__ W_agg_w,    // (E,E)
    const float* __restrict__ Wq,         // (H,E,E)
    const float* __restrict__ Wk,         // (H,E,E)
    float* __restrict__ qout,             // (2,H,B,E)
    float* __restrict__ K_supp)           // (H,SUPP,E)
{
    const int tid  = threadIdx.x;
    const int lane = tid & 63;
    const int wave = tid >> 6;

    if (blockIdx.y == 2) {
        // ---------------- ksupp plane ----------------
        // wave == head.  Wk column for this lane held in 64 VGPRs; 8 supp
        // rows staged to LDS per iteration (2 gathers per wave), every head
        // consumes all 8 rows in 2 groups of 4 (register discipline).
        __shared__ __align__(16) float sEv[8][E];
        const int h = wave;
        float wkc[E];
#pragma unroll
        for (int i = 0; i < E; i++) wkc[i] = Wk[h * E * E + i * E + lane];

        for (int j0 = blockIdx.x * 8; j0 < SUPP; j0 += gridDim.x * 8) {
#pragma unroll
            for (int t = 0; t < 2; t++) {
                const int jm = j0 + 2 * wave + t;
                if (jm < SUPP) {
                    const int u = supp_users[jm];
                    sEv[2 * wave + t][lane] = tgt_user_emb[(size_t)u * E + lane];
                }
            }
            __syncthreads();

#pragma unroll 1
            for (int g = 0; g < 2; g++) {
                float a0 = 0.f, a1 = 0.f, a2 = 0.f, a3 = 0.f;
#pragma unroll
                for (int k = 0; k < 16; k++) {
                    const float4 v0 = *(const float4*)&sEv[4 * g + 0][4 * k];
                    const float4 v1 = *(const float4*)&sEv[4 * g + 1][4 * k];
                    const float4 v2 = *(const float4*)&sEv[4 * g + 2][4 * k];
                    const float4 v3 = *(const float4*)&sEv[4 * g + 3][4 * k];
                    const float w0 = wkc[4 * k + 0], w1 = wkc[4 * k + 1];
                    const float w2 = wkc[4 * k + 2], w3 = wkc[4 * k + 3];
                    a0 = fmaf(v0.w, w3, fmaf(v0.z, w2, fmaf(v0.y, w1, fmaf(v0.x, w0, a0))));
                    a1 = fmaf(v1.w, w3, fmaf(v1.z, w2, fmaf(v1.y, w1, fmaf(v1.x, w0, a1))));
                    a2 = fmaf(v2.w, w3, fmaf(v2.z, w2, fmaf(v2.y, w1, fmaf(v2.x, w0, a2))));
                    a3 = fmaf(v3.w, w3, fmaf(v3.z, w2, fmaf(v3.y, w1, fmaf(v3.x, w0, a3))));
                }
                const int jb = j0 + 4 * g;
                if (jb + 0 < SUPP) K_supp[((size_t)h * SUPP + jb + 0) * E + lane] = a0;
                if (jb + 1 < SUPP) K_supp[((size_t)h * SUPP + jb + 1) * E + lane] = a1;
                if (jb + 2 < SUPP) K_supp[((size_t)h * SUPP + jb + 2) * E + lane] = a2;
                if (jb + 3 < SUPP) K_supp[((size_t)h * SUPP + jb + 3) * E + lane] = a3;
            }
            __syncthreads();  // before sEv is overwritten
        }
        return;
    }

    // ---------------- encode + q plane ----------------
    __shared__ __align__(16) float sHist[LP * E];   // 13 KB
    __shared__ float sAtt[LP];
    __shared__ float sPart[4][E];
    __shared__ __align__(16) float sOut[E];
    __shared__ __align__(16) float sFea[E];

    const int b    = blockIdx.x;
    const int call = blockIdx.y;

    const int* his = call ? tgt_his : src_his;
    const int* hl  = call ? tgt_hl  : src_hl;
    const float* user_table = call ? tgt_user_emb : src_user_emb;

    // W_att column for this lane: 64 VGPRs, const-indexed only.
    float wcol[E];
#pragma unroll
    for (int i = 0; i < E; i++) wcol[i] = W_att_w[i * E + lane];

    const int uid    = x[2 * b];
    const float uv   = user_table[(size_t)uid * E + lane];
    const float bias = W_att_b[lane];
    const int hlen   = hl[b];

    // phase 1a: gather + stage own rows (l = wave + 4r); rows >= hlen are 0.
#pragma unroll
    for (int r = 0; r < RW; r++) {
        const int l  = wave + 4 * r;
        const int it = (l < L) ? his[b * L + l] : 0;
        const float hv = (l < hlen) ? item_emb[(size_t)it * E + lane] : 0.0f;
        sHist[l * E + lane] = hv;
    }
    __syncthreads();

    // phase 1b: key matmul per row -- register weights x uniform LDS float4
    // broadcasts; outer row loop NOT unrolled (register cap).
#pragma unroll 1
    for (int r = 0; r < RW; r++) {
        const int l = wave + 4 * r;
        if (l >= L) continue;   // wave-uniform branch
        float a0 = 0.f, a1 = 0.f, a2 = 0.f, a3 = 0.f;
#pragma unroll
        for (int k = 0; k < 16; k++) {
            const float4 h4 = *(const float4*)&sHist[l * E + 4 * k];
            a0 = fmaf(h4.x, wcol[4 * k + 0], a0);
            a1 = fmaf(h4.y, wcol[4 * k + 1], a1);
            a2 = fmaf(h4.z, wcol[4 * k + 2], a2);
            a3 = fmaf(h4.w, wcol[4 * k + 3], a3);
        }
        float part = tanh_fast((a0 + a1) + (a2 + a3) + bias) * uv;
#pragma unroll
        for (int off = 32; off; off >>= 1) part += __shfl_xor(part, off);
        if (lane == 0) sAtt[l] = (l < hlen) ? part : 0.0f;
    }
    __syncthreads();

    // softmax denom, redundant per wave (no max-subtract per reference;
    // padded rows contribute exp(0)=1; +1e-12).
    const float vex = (lane < L) ? __expf(sAtt[lane]) : 0.0f;
    float sden = vex;
#pragma unroll
    for (int off = 32; off; off >>= 1) sden += __shfl_xor(sden, off);
    const float rden = __builtin_amdgcn_rcpf(sden + 1e-12f);

    // ctx partials: own rows; att weight for row l lives in lane l of vex.
    float c = 0.0f;
#pragma unroll
    for (int r = 0; r < RW; r++) {
        const int l = wave + 4 * r;
        const float p = (l < L) ? lanebc(vex, l) * rden : 0.0f;
        c = fmaf(p, sHist[l * E + lane], c);
    }
    sPart[wave][lane] = c;
    __syncthreads();
    if (tid < E) sOut[tid] = (sPart[0][tid] + sPart[1][tid]) + (sPart[2][tid] + sPart[3][tid]);
    __syncthreads();

    // agg: fea = ctx @ W_agg, i-range split across waves (16 i's each).
    {
        const float4* o4 = (const float4*)&sOut[wave * 16];
        float g0 = 0.0f, g1 = 0.0f, g2 = 0.0f, g3 = 0.0f;
#pragma unroll
        for (int k = 0; k < 4; k++) {
            const float4 v = o4[k];
            const float* wr = W_agg_w + (wave * 16 + 4 * k) * E + lane;
            g0 += v.x * wr[0];
            g1 += v.y * wr[E];
            g2 += v.z * wr[2 * E];
            g3 += v.w * wr[3 * E];
        }
        sPart[wave][lane] = (g0 + g1) + (g2 + g3);
    }
    __syncthreads();
    if (tid < E) sFea[tid] = (sPart[0][tid] + sPart[1][tid]) + (sPart[2][tid] + sPart[3][tid]);
    __syncthreads();

    // q projection, wave == head (uniform float4 LDS broadcast of fea).
    {
        const float* Wqh = Wq + wave * E * E;
        const float4* f4p = (const float4*)sFea;
        float q0 = 0.0f, q1 = 0.0f, q2 = 0.0f, q3 = 0.0f;
#pragma unroll
        for (int k = 0; k < 16; k++) {
            const float4 f4 = f4p[k];
            const float* wr = Wqh + (4 * k) * E + lane;
            q0 += f4.x * wr[0];
            q1 += f4.y * wr[E];
            q2 += f4.z * wr[2 * E];
            q3 += f4.w * wr[3 * E];
        }
        qout[(((call * H) + wave) * B + b) * E + lane] = (q0 + q1) + (q2 + q3);
    }
}

// ---------------------------------------------------------------------------
// Kernel 2: attention per (b,h,call).  K tile lives in REGISTERS:
// lane = (rsub = lane>>4, u = lane&15); wave w owns rows [w*64,(w+1)*64);
// kreg[i] = row (s0+4i+rsub), unit u (4 floats).  Gathers are issued as a
// batch of 16 (all in flight) before any dependent reduce.  softmax =
// jax.nn.softmax (max-subtracted).  ctx is pure-VALU FMA over the register
// tile; ctx uses k itself (reference quirk); g = ctx @ Wv[h].
//
// XCD pinning: grid flattened to 8192 blocks; (h,call) = blockIdx & 7 so all
// consumers of head h's 2.56 MB K table land on one XCD's 4 MB L2.
// ---------------------------------------------------------------------------
__global__ __launch_bounds__(256) void attn_kernel(
    const int* __restrict__ sample_idx,  // (2,H,B,S)
    const float* __restrict__ K_supp,    // (H,SUPP,E)
    const float* __restrict__ qarr,      // (2,H,B,E)
    const float* __restrict__ Wv,        // (H,E,E)
    float* __restrict__ gout)            // (2,B,H*E)
{
    __shared__ float sRed[8];
    __shared__ float sCtx[4][E];
    __shared__ float sC[E];
    __shared__ float sG[4][E];

    const int n    = blockIdx.x;
    const int xcd  = n & 7;
    const int h    = xcd >> 1;
    const int call = xcd & 1;
    const int b    = n >> 3;
    const int tid  = threadIdx.x;
    const int lane = tid & 63;
    const int wave = tid >> 6;
    const int u    = lane & 15;
    const int rsub = lane >> 4;
    const int s0   = wave * 64;

    const int* idx = sample_idx + (((call * H) + h) * B + b) * S;
    const float* Kh = K_supp + (size_t)h * SUPP * E;
    const float4 qu = *(const float4*)(qarr + ((size_t)(((call * H) + h) * B + b)) * E + 4 * u);

    // ---- batched gather: idx loads, then 16 independent row gathers ----
    int jr[16];
#pragma unroll
    for (int i = 0; i < 16; i++) jr[i] = idx[s0 + 4 * i + rsub];
    float4 kreg[16];
#pragma unroll
    for (int i = 0; i < 16; i++)
        kreg[i] = *(const float4*)(Kh + (size_t)jr[i] * E + 4 * u);

    // ---- logits: in-lane partial dot + 4-step reduce per 16-lane group ----
    float mylogit = 0.0f;
#pragma unroll
    for (int i = 0; i < 16; i++) {
        float part = kreg[i].x * qu.x + kreg[i].y * qu.y
                   + kreg[i].z * qu.z + kreg[i].w * qu.w;
#pragma unroll
        for (int off = 1; off < 16; off <<= 1) part += __shfl_xor(part, off);
        mylogit = (u == i) ? part : mylogit;   // lane holds row s0 + 4u + rsub
    }

    // ---- block softmax over 256 logits (permutation-invariant) ----
    float m = mylogit;
#pragma unroll
    for (int off = 32; off; off >>= 1) m = fmaxf(m, __shfl_xor(m, off));
    if (lane == 0) sRed[wave] = m;
    __syncthreads();
    const float mx = fmaxf(fmaxf(sRed[0], sRed[1]), fmaxf(sRed[2], sRed[3]));
    const float ex = __expf(mylogit - mx);
    float sm = ex;
#pragma unroll
    for (int off = 32; off; off >>= 1) sm += __shfl_xor(sm, off);
    if (lane == 0) sRed[4 + wave] = sm;
    __syncthreads();
    const float denom = sRed[4] + sRed[5] + sRed[6] + sRed[7];
    const float pval = ex / denom;   // weight of row s0 + 4u + rsub

    // ---- ctx: pure-VALU FMA over register tile ----
    // row s0+4i+rsub's weight lives at lane 16*rsub + i
    float4 cacc = make_float4(0.0f, 0.0f, 0.0f, 0.0f);
#pragma unroll
    for (int i = 0; i < 16; i++) {
        const float p = __shfl(pval, (lane & 48) + i);
        cacc.x += p * kreg[i].x;
        cacc.y += p * kreg[i].y;
        cacc.z += p * kreg[i].z;
        cacc.w += p * kreg[i].w;
    }
    // combine across rsub groups (lanes l, l^16, l^32, l^48 share unit u)
#pragma unroll
    for (int off = 16; off <= 32; off <<= 1) {
        cacc.x += __shfl_xor(cacc.x, off);
        cacc.y += __shfl_xor(cacc.y, off);
        cacc.z += __shfl_xor(cacc.z, off);
        cacc.w += __shfl_xor(cacc.w, off);
    }
    if (lane < 16) *(float4*)(&sCtx[wave][u * 4]) = cacc;
    __syncthreads();
    if (wave == 0) {
        sC[lane] = sCtx[0][lane] + sCtx[1][lane] + sCtx[2][lane] + sCtx[3][lane];
    }
    __syncthreads();

    // ---- g = ctx @ Wv[h], c-range split across waves ----
    const float* Wvh = Wv + h * E * E;
    float g = 0.0f;
#pragma unroll
    for (int k = 0; k < 16; k++) {
        const int c = wave * 16 + k;
        g += sC[c] * Wvh[c * E + lane];
    }
    sG[wave][lane] = g;
    __syncthreads();
    if (wave == 0) {
        gout[((size_t)(call * B) + b) * (H * E) + h * E + lane] =
            sG[0][lane] + sG[1][lane] + sG[2][lane] + sG[3][lane];
    }
}

// ---------------------------------------------------------------------------
// Kernel 3: W_out projection + final MLP + all four outputs.
// out layout: [output(B) | x3(B) | out_emb_s(B*E) | x2(B*E)]
// ---------------------------------------------------------------------------
__global__ __launch_bounds__(256) void final_kernel(
    const int* __restrict__ x,             // (B,2) [:,1]=item_id
    const float* __restrict__ tgt_item_emb,
    const float* __restrict__ gsrc,        // (B, H*E) -> user_emb path
    const float* __restrict__ gtgt,        // (B, H*E) -> hybrid path
    const float* __restrict__ W_out,       // (H*E, E)
    const float* __restrict__ l1_w,        // (2E, HID)
    const float* __restrict__ l1_b,        // (HID,)
    const float* __restrict__ l2_w,        // (HID, E)
    const float* __restrict__ l2_b,        // (E,)
    const float* __restrict__ l3_w,        // (E,1)
    const float* __restrict__ l3_b,        // (1,)
    float* __restrict__ out)
{
    __shared__ float sPart[4][E];
    __shared__ float sHyb[E];
    __shared__ float sItem[E];
    __shared__ float sX1[HID];

    const int b    = blockIdx.x;
    const int tid  = threadIdx.x;
    const int lane = tid & 63;
    const int wave = tid >> 6;

    if (tid < E) {
        const int item = x[2 * b + 1];
        sItem[tid] = tgt_item_emb[(size_t)item * E + tid];
    }

    const float* grow = (wave < 2) ? (gsrc + (size_t)b * (H * E))
                                   : (gtgt + (size_t)b * (H * E));
    const int i0 = (wave & 1) * 128;
    {
        const float4* g4 = (const float4*)(grow + i0);
        float a0 = 0.0f, a1 = 0.0f, a2 = 0.0f, a3 = 0.0f;
#pragma unroll
        for (int k = 0; k < 32; k++) {
            const float4 v = g4[k];
            const float* wr = W_out + (i0 + 4 * k) * E + lane;
            a0 += v.x * wr[0];
            a1 += v.y * wr[E];
            a2 += v.z * wr[2 * E];
            a3 += v.w * wr[3 * E];
        }
        sPart[wave][lane] = (a0 + a1) + (a2 + a3);
    }
    __syncthreads();

    if (wave == 0) {
        const float ue = sPart[0][lane] + sPart[1][lane];
        const float prod = ue * sItem[lane];
        out[2 * B + b * E + lane] = prod;  // out_emb_s
        float s = prod;
#pragma unroll
        for (int off = 32; off; off >>= 1) s += __shfl_xor(s, off);
        if (lane == 0) out[b] = s;         // output
    }
    if (wave == 1) {
        sHyb[lane] = sPart[2][lane] + sPart[3][lane];
    }
    __syncthreads();

    // l1: 128-deep sum split across 4 waves (waves 0,1: hybrid; 2,3: item)
    float a1 = 0.0f;
#pragma unroll
    for (int k = 0; k < 32; k++) {
        const int i = wave * 32 + k;
        const float v = (i < 64) ? sHyb[i] : sItem[i - 64];
        a1 += v * l1_w[i * HID + lane];
    }
    sPart[wave][lane] = a1;
    __syncthreads();

    if (wave == 0) {
        const float a = l1_b[lane] + sPart[0][lane] + sPart[1][lane]
                      + sPart[2][lane] + sPart[3][lane];
        sX1[lane] = tanh_fast(a);
    }
    __syncthreads();

    if (wave == 0) {
        float a = l2_b[lane];
#pragma unroll
        for (int i = 0; i < HID; i++) a += sX1[i] * l2_w[i * E + lane];
        const float x2 = tanh_fast(a);
        out[2 * B + B * E + b * E + lane] = x2;  // x2_t
        float p = x2 * l3_w[lane];
#pragma unroll
        for (int off = 32; off; off >>= 1) p += __shfl_xor(p, off);
        if (lane == 0) out[B + b] = p + l3_b[0]; // x3_t
    }
}

// ---------------------------------------------------------------------------
extern "C" void kernel_launch(void* const* d_in, const int* in_sizes, int n_in,
                              void* d_out, int out_size, void* d_ws, size_t ws_size,
                              hipStream_t stream) {
    const int*   x            = (const int*)d_in[0];
    const int*   src_his      = (const int*)d_in[1];
    const int*   src_hl       = (const int*)d_in[2];
    const int*   tgt_his      = (const int*)d_in[3];
    const int*   tgt_hl       = (const int*)d_in[4];
    const int*   sample_idx   = (const int*)d_in[5];
    const int*   supp_users   = (const int*)d_in[6];
    const float* src_user_emb = (const float*)d_in[7];
    const float* src_item_emb = (const float*)d_in[8];
    const float* tgt_user_emb = (const float*)d_in[9];
    const float* tgt_item_emb = (const float*)d_in[10];
    const float* W_att_w      = (const float*)d_in[11];
    const float* W_att_b      = (const float*)d_in[12];
    const float* W_agg_w      = (const float*)d_in[13];
    const float* Wq           = (const float*)d_in[14];
    const float* Wk           = (const float*)d_in[15];
    const float* Wv           = (const float*)d_in[16];
    const float* W_out        = (const float*)d_in[17];
    const float* l1_w         = (const float*)d_in[18];
    const float* l1_b         = (const float*)d_in[19];
    const float* l2_w         = (const float*)d_in[20];
    const float* l2_b         = (const float*)d_in[21];
    const float* l3_w         = (const float*)d_in[22];
    const float* l3_b         = (const float*)d_in[23];

    float* ws      = (float*)d_ws;
    float* qarr    = ws;                                  // 2*H*B*E
    float* K_supp  = qarr + 2 * H * B * E;                // H*SUPP*E
    float* garr    = K_supp + H * SUPP * E;               // 2*B*H*E
    float* out     = (float*)d_out;

    pre_kernel<<<dim3(B, 3), 256, 0, stream>>>(
        x, src_his, src_hl, tgt_his, tgt_hl, src_item_emb,
        src_user_emb, tgt_user_emb, supp_users,
        W_att_w, W_att_b, W_agg_w, Wq, Wk, qarr, K_supp);
    attn_kernel<<<dim3(B * H * 2), 256, 0, stream>>>(
        sample_idx, K_supp, qarr, Wv, garr);
    final_kernel<<<dim3(B), 256, 0, stream>>>(
        x, tgt_item_emb, garr, garr + B * H * E, W_out,
        l1_w, l1_b, l2_w, l2_b, l3_w, l3_b, out);
}

// Round 6
// 261.407 us; speedup vs baseline: 1.7182x; 1.7182x over previous
//
#include <hip/hip_runtime.h>

// Problem constants (from reference)
constexpr int B    = 1024;
constexpr int L    = 50;
constexpr int S    = 256;
constexpr int H    = 4;
constexpr int E    = 64;
constexpr int HID  = 64;
constexpr int SUPP = 10000;

// Branch-free tanh via exp2-based __expf; clamp keeps e finite. Rel err ~1e-6.
__device__ __forceinline__ float tanh_fast(float x) {
    const float xc = fminf(fmaxf(x, -15.0f), 15.0f);
    const float e  = __expf(2.0f * xc);
    return (e - 1.0f) * __builtin_amdgcn_rcpf(e + 1.0f);
}

// Broadcast lane l's value (l wave-uniform) -> v_readlane -> SGPR.
__device__ __forceinline__ float lanebc(float v, int l) {
    return __int_as_float(__builtin_amdgcn_readlane(__float_as_int(v), l));
}

// ---------------------------------------------------------------------------
// Kernel 1: fused pre-work.  256 threads (4 waves), plain __launch_bounds__.
// CODEGEN RULE (rounds 0-5 evidence): the 64-float per-lane weight column
// stays register-resident ONLY in this exact shape -- plain launch bounds
// (VGPR=72, no spill, round 0); any of {__launch_bounds__(...,N) hints,
// float4 temps in the hot loop, multi-row accumulator blocking, un-unrolled
// loops around the array} demotes it to global reloads (r1: VGPR=60) or
// scratch spill (r2: 750MB, r4: 214MB, r5: 444MB).  Hot loops below are
// byte-for-byte round 0's: readlane broadcast x wcol[i], single accumulator.
//
//   blockIdx.y in {0,1}: user_fea_encode(call=y) + per-head q projection
//     (wave == head); fea never touches global memory.
//   blockIdx.y == 2:     K_supp[h][j][:] = tgt_user_emb[supp_users[j]] @ Wk[h]
//
// Algebraic deltas vs round 0 (each validated in later passing rounds):
//  - padded rows (l >= hlen) skip gather+dot entirely: reference zeroes hist
//    rows >= hlen, so their logit is overwritten with 0 and their ctx
//    contribution is 0 via hist=0.  Mean hlen ~ L/2 -> phase-1b work halves.
//  - hist.sum(-1)==0 pad test == (l >= hlen) a.s. (Gaussian embeddings).
//  - tanh_fast / __expf.
//  - softmax denom computed redundantly per wave (one barrier fewer, no
//    wave0-serial phase).  Encoder softmax per reference: no max-subtract,
//    padded rows contribute exp(0)=1, denom + 1e-12.
// ---------------------------------------------------------------------------
__global__ __launch_bounds__(256) void pre_kernel(
    const int* __restrict__ x,            // (B,2)  [:,0]=user_id
    const int* __restrict__ src_his,      // (B,L)
    const int* __restrict__ src_hl,       // (B,)
    const int* __restrict__ tgt_his,      // (B,L)
    const int* __restrict__ tgt_hl,       // (B,)
    const float* __restrict__ item_emb,   // src_item_emb -- always src!
    const float* __restrict__ src_user_emb,
    const float* __restrict__ tgt_user_emb,
    const int* __restrict__ supp_users,   // (SUPP,)
    const float* __restrict__ W_att_w,    // (E,E)
    const float* __restrict__ W_att_b,    // (E,)
    const float* __restrict__ W_agg_w,    // (E,E)
    const float* __restrict__ Wq,         // (H,E,E)
    const float* __restrict__ Wk,         // (H,E,E)
    float* __restrict__ qout,             // (2,H,B,E)
    float* __restrict__ K_supp)           // (H,SUPP,E)
{
    const int tid  = threadIdx.x;
    const int lane = tid & 63;
    const int wave = tid >> 6;

    if (blockIdx.y == 2) {
        // ---------------- ksupp plane (round-0 verbatim) ----------------
        const int h = wave;   // wave == head
        float wcol[E];
#pragma unroll
        for (int i = 0; i < E; i++) wcol[i] = Wk[h * E * E + i * E + lane];

#pragma unroll 2
        for (int j = blockIdx.x; j < SUPP; j += gridDim.x) {
            const int u = supp_users[j];
            const float ev = tgt_user_emb[(size_t)u * E + lane];
            float acc = 0.0f;
#pragma unroll
            for (int i = 0; i < E; i++) acc += lanebc(ev, i) * wcol[i];
            K_supp[((size_t)h * SUPP + j) * E + lane] = acc;
        }
        return;
    }

    // ---------------- encode + q plane ----------------
    __shared__ float sHist[L * E];
    __shared__ float sAtt[64];
    __shared__ float sPart[4][E];
    __shared__ float sOut[E];

    const int b    = blockIdx.x;
    const int call = blockIdx.y;

    const int* his = call ? tgt_his : src_his;
    const int* hl  = call ? tgt_hl  : src_hl;
    const float* user_table = call ? tgt_user_emb : src_user_emb;

    float wcol[E];
#pragma unroll
    for (int i = 0; i < E; i++) wcol[i] = W_att_w[i * E + lane];

    const int uid    = x[2 * b];
    const float uv   = user_table[(size_t)uid * E + lane];
    const float bias = W_att_b[lane];
    const int hlen   = hl[b];

    // phase 1: per valid history row -- gather, stage, key-matmul, att logit.
    // Rows >= hlen: logit 0, never staged, never read (ctx skips them).
    for (int l = wave; l < L; l += 4) {
        if (l < hlen) {
            const int it = his[b * L + l];
            const float hv = item_emb[(size_t)it * E + lane];
            sHist[l * E + lane] = hv;
            float a = bias;
#pragma unroll
            for (int i = 0; i < E; i++) a += lanebc(hv, i) * wcol[i];
            float part = tanh_fast(a) * uv;
#pragma unroll
            for (int off = 32; off; off >>= 1) part += __shfl_xor(part, off);
            if (lane == 0) sAtt[l] = part;
        } else {
            if (lane == 0) sAtt[l] = 0.0f;
        }
    }
    __syncthreads();

    // softmax denom, redundant per wave (no max-subtract; pads exp(0)=1).
    const float vex = (lane < L) ? __expf(sAtt[lane]) : 0.0f;
    float sden = vex;
#pragma unroll
    for (int off = 32; off; off >>= 1) sden += __shfl_xor(sden, off);
    const float rden = __builtin_amdgcn_rcpf(sden + 1e-12f);

    // ctx partials across waves; rows >= hlen contribute 0 via hist=0 -> skip.
    float c = 0.0f;
    for (int l = wave; l < hlen; l += 4)
        c = fmaf(lanebc(vex, l) * rden, sHist[l * E + lane], c);
    sPart[wave][lane] = c;
    __syncthreads();
    if (tid < E) sOut[tid] = sPart[0][tid] + sPart[1][tid] + sPart[2][tid] + sPart[3][tid];
    __syncthreads();

    // agg: fea = ctx @ W_agg, i-range split across waves (round-0 verbatim).
    float g = 0.0f;
#pragma unroll
    for (int k = 0; k < 16; k++) {
        const int i = wave * 16 + k;
        g += sOut[i] * W_agg_w[i * E + lane];
    }
    sPart[wave][lane] = g;
    __syncthreads();

    // fea[lane] (every wave computes it; then q projection, wave == head).
    const float fval = sPart[0][lane] + sPart[1][lane] + sPart[2][lane] + sPart[3][lane];
    const float* Wqh = Wq + wave * E * E;
    float qacc = 0.0f;
#pragma unroll
    for (int i = 0; i < E; i++) qacc += lanebc(fval, i) * Wqh[i * E + lane];
    qout[(((call * H) + wave) * B + b) * E + lane] = qacc;
}

// ---------------------------------------------------------------------------
// Kernel 2: attention per (b,h,call).  K tile lives in REGISTERS:
// lane = (rsub = lane>>4, u = lane&15); wave w owns rows [w*64,(w+1)*64);
// kreg[i] = row (s0+4i+rsub), unit u (4 floats).  Gathers are issued as a
// batch of 16 (all in flight) before any dependent reduce.  softmax =
// jax.nn.softmax (max-subtracted).  ctx is pure-VALU FMA over the register
// tile; ctx uses k itself (reference quirk); g = ctx @ Wv[h].
//
// XCD pinning: grid flattened to 8192 blocks; (h,call) = blockIdx & 7 so all
// consumers of head h's 2.56 MB K table land on one XCD's 4 MB L2.
// ---------------------------------------------------------------------------
__global__ __launch_bounds__(256) void attn_kernel(
    const int* __restrict__ sample_idx,  // (2,H,B,S)
    const float* __restrict__ K_supp,    // (H,SUPP,E)
    const float* __restrict__ qarr,      // (2,H,B,E)
    const float* __restrict__ Wv,        // (H,E,E)
    float* __restrict__ gout)            // (2,B,H*E)
{
    __shared__ float sRed[8];
    __shared__ float sCtx[4][E];
    __shared__ float sC[E];
    __shared__ float sG[4][E];

    const int n    = blockIdx.x;
    const int xcd  = n & 7;
    const int h    = xcd >> 1;
    const int call = xcd & 1;
    const int b    = n >> 3;
    const int tid  = threadIdx.x;
    const int lane = tid & 63;
    const int wave = tid >> 6;
    const int u    = lane & 15;
    const int rsub = lane >> 4;
    const int s0   = wave * 64;

    const int* idx = sample_idx + (((call * H) + h) * B + b) * S;
    const float* Kh = K_supp + (size_t)h * SUPP * E;
    const float4 qu = *(const float4*)(qarr + ((size_t)(((call * H) + h) * B + b)) * E + 4 * u);

    // ---- batched gather: idx loads, then 16 independent row gathers ----
    int jr[16];
#pragma unroll
    for (int i = 0; i < 16; i++) jr[i] = idx[s0 + 4 * i + rsub];
    float4 kreg[16];
#pragma unroll
    for (int i = 0; i < 16; i++)
        kreg[i] = *(const float4*)(Kh + (size_t)jr[i] * E + 4 * u);

    // ---- logits: in-lane partial dot + 4-step reduce per 16-lane group ----
    float mylogit = 0.0f;
#pragma unroll
    for (int i = 0; i < 16; i++) {
        float part = kreg[i].x * qu.x + kreg[i].y * qu.y
                   + kreg[i].z * qu.z + kreg[i].w * qu.w;
#pragma unroll
        for (int off = 1; off < 16; off <<= 1) part += __shfl_xor(part, off);
        mylogit = (u == i) ? part : mylogit;   // lane holds row s0 + 4u + rsub
    }

    // ---- block softmax over 256 logits (permutation-invariant) ----
    float m = mylogit;
#pragma unroll
    for (int off = 32; off; off >>= 1) m = fmaxf(m, __shfl_xor(m, off));
    if (lane == 0) sRed[wave] = m;
    __syncthreads();
    const float mx = fmaxf(fmaxf(sRed[0], sRed[1]), fmaxf(sRed[2], sRed[3]));
    const float ex = __expf(mylogit - mx);
    float sm = ex;
#pragma unroll
    for (int off = 32; off; off >>= 1) sm += __shfl_xor(sm, off);
    if (lane == 0) sRed[4 + wave] = sm;
    __syncthreads();
    const float denom = sRed[4] + sRed[5] + sRed[6] + sRed[7];
    const float pval = ex / denom;   // weight of row s0 + 4u + rsub

    // ---- ctx: pure-VALU FMA over register tile ----
    // row s0+4i+rsub's weight lives at lane 16*rsub + i
    float4 cacc = make_float4(0.0f, 0.0f, 0.0f, 0.0f);
#pragma unroll
    for (int i = 0; i < 16; i++) {
        const float p = __shfl(pval, (lane & 48) + i);
        cacc.x += p * kreg[i].x;
        cacc.y += p * kreg[i].y;
        cacc.z += p * kreg[i].z;
        cacc.w += p * kreg[i].w;
    }
    // combine across rsub groups (lanes l, l^16, l^32, l^48 share unit u)
#pragma unroll
    for (int off = 16; off <= 32; off <<= 1) {
        cacc.x += __shfl_xor(cacc.x, off);
        cacc.y += __shfl_xor(cacc.y, off);
        cacc.z += __shfl_xor(cacc.z, off);
        cacc.w += __shfl_xor(cacc.w, off);
    }
    if (lane < 16) *(float4*)(&sCtx[wave][u * 4]) = cacc;
    __syncthreads();
    if (wave == 0) {
        sC[lane] = sCtx[0][lane] + sCtx[1][lane] + sCtx[2][lane] + sCtx[3][lane];
    }
    __syncthreads();

    // ---- g = ctx @ Wv[h], c-range split across waves ----
    const float* Wvh = Wv + h * E * E;
    float g = 0.0f;
#pragma unroll
    for (int k = 0; k < 16; k++) {
        const int c = wave * 16 + k;
        g += sC[c] * Wvh[c * E + lane];
    }
    sG[wave][lane] = g;
    __syncthreads();
    if (wave == 0) {
        gout[((size_t)(call * B) + b) * (H * E) + h * E + lane] =
            sG[0][lane] + sG[1][lane] + sG[2][lane] + sG[3][lane];
    }
}

// ---------------------------------------------------------------------------
// Kernel 3: W_out projection + final MLP + all four outputs.
// out layout: [output(B) | x3(B) | out_emb_s(B*E) | x2(B*E)]
// ---------------------------------------------------------------------------
__global__ __launch_bounds__(256) void final_kernel(
    const int* __restrict__ x,             // (B,2) [:,1]=item_id
    const float* __restrict__ tgt_item_emb,
    const float* __restrict__ gsrc,        // (B, H*E) -> user_emb path
    const float* __restrict__ gtgt,        // (B, H*E) -> hybrid path
    const float* __restrict__ W_out,       // (H*E, E)
    const float* __restrict__ l1_w,        // (2E, HID)
    const float* __restrict__ l1_b,        // (HID,)
    const float* __restrict__ l2_w,        // (HID, E)
    const float* __restrict__ l2_b,        // (E,)
    const float* __restrict__ l3_w,        // (E,1)
    const float* __restrict__ l3_b,        // (1,)
    float* __restrict__ out)
{
    __shared__ float sPart[4][E];
    __shared__ float sHyb[E];
    __shared__ float sItem[E];
    __shared__ float sX1[HID];

    const int b    = blockIdx.x;
    const int tid  = threadIdx.x;
    const int lane = tid & 63;
    const int wave = tid >> 6;

    if (tid < E) {
        const int item = x[2 * b + 1];
        sItem[tid] = tgt_item_emb[(size_t)item * E + tid];
    }

    const float* grow = (wave < 2) ? (gsrc + (size_t)b * (H * E))
                                   : (gtgt + (size_t)b * (H * E));
    const int i0 = (wave & 1) * 128;
    {
        const float4* g4 = (const float4*)(grow + i0);
        float a0 = 0.0f, a1 = 0.0f, a2 = 0.0f, a3 = 0.0f;
#pragma unroll
        for (int k = 0; k < 32; k++) {
            const float4 v = g4[k];
            const float* wr = W_out + (i0 + 4 * k) * E + lane;
            a0 += v.x * wr[0];
            a1 += v.y * wr[E];
            a2 += v.z * wr[2 * E];
            a3 += v.w * wr[3 * E];
        }
        sPart[wave][lane] = (a0 + a1) + (a2 + a3);
    }
    __syncthreads();

    if (wave == 0) {
        const float ue = sPart[0][lane] + sPart[1][lane];
        const float prod = ue * sItem[lane];
        out[2 * B + b * E + lane] = prod;  // out_emb_s
        float s = prod;
#pragma unroll
        for (int off = 32; off; off >>= 1) s += __shfl_xor(s, off);
        if (lane == 0) out[b] = s;         // output
    }
    if (wave == 1) {
        sHyb[lane] = sPart[2][lane] + sPart[3][lane];
    }
    __syncthreads();

    // l1: 128-deep sum split across 4 waves (waves 0,1: hybrid; 2,3: item)
    float a1 = 0.0f;
#pragma unroll
    for (int k = 0; k < 32; k++) {
        const int i = wave * 32 + k;
        const float v = (i < 64) ? sHyb[i] : sItem[i - 64];
        a1 += v * l1_w[i * HID + lane];
    }
    sPart[wave][lane] = a1;
    __syncthreads();

    if (wave == 0) {
        const float a = l1_b[lane] + sPart[0][lane] + sPart[1][lane]
                      + sPart[2][lane] + sPart[3][lane];
        sX1[lane] = tanh_fast(a);
    }
    __syncthreads();

    if (wave == 0) {
        float a = l2_b[lane];
#pragma unroll
        for (int i = 0; i < HID; i++) a += sX1[i] * l2_w[i * E + lane];
        const float x2 = tanh_fast(a);
        out[2 * B + B * E + b * E + lane] = x2;  // x2_t
        float p = x2 * l3_w[lane];
#pragma unroll
        for (int off = 32; off; off >>= 1) p += __shfl_xor(p, off);
        if (lane == 0) out[B + b] = p + l3_b[0]; // x3_t
    }
}

// ---------------------------------------------------------------------------
extern "C" void kernel_launch(void* const* d_in, const int* in_sizes, int n_in,
                              void* d_out, int out_size, void* d_ws, size_t ws_size,
                              hipStream_t stream) {
    const int*   x            = (const int*)d_in[0];
    const int*   src_his      = (const int*)d_in[1];
    const int*   src_hl       = (const int*)d_in[2];
    const int*   tgt_his      = (const int*)d_in[3];
    const int*   tgt_hl       = (const int*)d_in[4];
    const int*   sample_idx   = (const int*)d_in[5];
    const int*   supp_users   = (const int*)d_in[6];
    const float* src_user_emb = (const float*)d_in[7];
    const float* src_item_emb = (const float*)d_in[8];
    const float* tgt_user_emb = (const float*)d_in[9];
    const float* tgt_item_emb = (const float*)d_in[10];
    const float* W_att_w      = (const float*)d_in[11];
    const float* W_att_b      = (const float*)d_in[12];
    const float* W_agg_w      = (const float*)d_in[13];
    const float* Wq           = (const float*)d_in[14];
    const float* Wk           = (const float*)d_in[15];
    const float* Wv           = (const float*)d_in[16];
    const float* W_out        = (const float*)d_in[17];
    const float* l1_w         = (const float*)d_in[18];
    const float* l1_b         = (const float*)d_in[19];
    const float* l2_w         = (const float*)d_in[20];
    const float* l2_b         = (const float*)d_in[21];
    const float* l3_w         = (const float*)d_in[22];
    const float* l3_b         = (const float*)d_in[23];

    float* ws      = (float*)d_ws;
    float* qarr    = ws;                                  // 2*H*B*E
    float* K_supp  = qarr + 2 * H * B * E;                // H*SUPP*E
    float* garr    = K_supp + H * SUPP * E;               // 2*B*H*E
    float* out     = (float*)d_out;

    pre_kernel<<<dim3(B, 3), 256, 0, stream>>>(
        x, src_his, src_hl, tgt_his, tgt_hl, src_item_emb,
        src_user_emb, tgt_user_emb, supp_users,
        W_att_w, W_att_b, W_agg_w, Wq, Wk, qarr, K_supp);
    attn_kernel<<<dim3(B * H * 2), 256, 0, stream>>>(
        sample_idx, K_supp, qarr, Wv, garr);
    final_kernel<<<dim3(B), 256, 0, stream>>>(
        x, tgt_item_emb, garr, garr + B * H * E, W_out,
        l1_w, l1_b, l2_w, l2_b, l3_w, l3_b, out);
}